// Round 1
// baseline (1848.618 us; speedup 1.0000x reference)
//
#include <hip/hip_runtime.h>

typedef unsigned short u16;
typedef unsigned int u32;

#define NPTS 131072
#define CD 128
#define KOFF 27
#define MMAP 65536
#define LDAB 136  // LDS row stride in u16: 128 + 8 pad -> 272B rows, 2-way-max bank aliasing (free)

__device__ __forceinline__ u16 f2bf(float f) {  // f32 -> bf16 RNE
  u32 u = __float_as_uint(f);
  u32 r = (u + 0x7fffu + ((u >> 16) & 1u)) >> 16;
  return (u16)r;
}

typedef __attribute__((ext_vector_type(8))) short bf16x8;
typedef __attribute__((ext_vector_type(4))) float f32x4;

// ---------------- dtype conversion ----------------
__global__ __launch_bounds__(256) void k_convert_x(const float* __restrict__ x,
                                                   u16* __restrict__ xb) {
  long i = ((long)blockIdx.x * 256 + threadIdx.x) * 8;
  float4 a = *(const float4*)(x + i);
  float4 b = *(const float4*)(x + i + 4);
  uint4 v;
  v.x = f2bf(a.x) | ((u32)f2bf(a.y) << 16);
  v.y = f2bf(a.z) | ((u32)f2bf(a.w) << 16);
  v.z = f2bf(b.x) | ((u32)f2bf(b.y) << 16);
  v.w = f2bf(b.z) | ((u32)f2bf(b.w) << 16);
  *(uint4*)(xb + i) = v;
}

// W [K][ci][co] f32  ->  Wb [K][co][ci] bf16 (transposed so B-fragments are contiguous)
__global__ __launch_bounds__(256) void k_convert_w(const float* __restrict__ W,
                                                   u16* __restrict__ Wb) {
  int idx = blockIdx.x * 256 + threadIdx.x;  // chunk id, KOFF*2048 total
  if (idx >= KOFF * 2048) return;
  int k = idx >> 11;
  int rem = idx & 2047;
  int co = rem >> 4;
  int cc = rem & 15;  // chunk of 8 ci
  const float* ws = W + (long)k * (CD * CD) + (long)(cc * 8) * CD + co;
  u16 t[8];
#pragma unroll
  for (int j = 0; j < 8; ++j) t[j] = f2bf(ws[j * CD]);
  uint4 v;
  v.x = t[0] | ((u32)t[1] << 16);
  v.y = t[2] | ((u32)t[3] << 16);
  v.z = t[4] | ((u32)t[5] << 16);
  v.w = t[6] | ((u32)t[7] << 16);
  ((uint4*)Wb)[idx] = v;
}

// ---------------- gather-GEMM (dense contrib out, no atomics) ----------------
// block: 256 thr, tile 64 rows x 128 cols, full K=C=128 staged once.
__global__ __launch_bounds__(256) void k_gemm(const u16* __restrict__ src,   // [N,128] bf16
                                              const u16* __restrict__ Wb,    // [K][co][ci] bf16
                                              const int* __restrict__ map_in,
                                              u16* __restrict__ contrib,     // [kc*M,128] bf16
                                              int kbase) {
  __shared__ u16 As[64 * LDAB];
  __shared__ u16 Bs[128 * LDAB];
  const int t = threadIdx.x;
  const int krel = blockIdx.y;
  const int k = kbase + krel;
  const long m0 = (long)blockIdx.x * 64;
  const int* mi = map_in + (long)k * MMAP + m0;

  const uint4* wsrc = (const uint4*)(Wb + (long)k * (CD * CD));
#pragma unroll
  for (int i = 0; i < 8; ++i) {  // stage B: 2048 16B chunks
    int q = i * 256 + t;
    int co = q >> 4, c = q & 15;
    *(uint4*)&Bs[co * LDAB + c * 8] = wsrc[q];
  }
#pragma unroll
  for (int i = 0; i < 4; ++i) {  // stage A (gathered): 1024 chunks
    int q = i * 256 + t;
    int r = q >> 4, c = q & 15;
    long row = mi[r];
    *(uint4*)&As[r * LDAB + c * 8] = ((const uint4*)(src + row * CD))[c];
  }
  __syncthreads();

  const int wave = t >> 6, lane = t & 63;
  const int lr = lane & 15, quad = lane >> 4;
  const int wm = (wave & 1) * 32;   // 2x2 wave grid: 32 rows x 64 cols each
  const int wn = (wave >> 1) * 64;
  f32x4 acc[2][4] = {};
#pragma unroll
  for (int kk = 0; kk < 4; ++kk) {
    bf16x8 a[2], b[4];
#pragma unroll
    for (int mt = 0; mt < 2; ++mt)
      a[mt] = *(const bf16x8*)&As[(wm + mt * 16 + lr) * LDAB + (kk * 4 + quad) * 8];
#pragma unroll
    for (int nt = 0; nt < 4; ++nt)
      b[nt] = *(const bf16x8*)&Bs[(wn + nt * 16 + lr) * LDAB + (kk * 4 + quad) * 8];
#pragma unroll
    for (int mt = 0; mt < 2; ++mt)
#pragma unroll
      for (int nt = 0; nt < 4; ++nt)
        acc[mt][nt] = __builtin_amdgcn_mfma_f32_16x16x32_bf16(a[mt], b[nt], acc[mt][nt], 0, 0, 0);
  }

  // C/D layout: col = lane&15, row = quad*4 + reg (m89-verified)
  const long gbase = (long)krel * MMAP + m0;
#pragma unroll
  for (int mt = 0; mt < 2; ++mt) {
#pragma unroll
    for (int v = 0; v < 4; ++v) {
      long g = gbase + wm + mt * 16 + quad * 4 + v;
      u16* orow = contrib + g * CD;
#pragma unroll
      for (int nt = 0; nt < 4; ++nt)
        orow[wn + nt * 16 + lr] = f2bf(acc[mt][nt][v]);
    }
  }
}

// ---------------- counting sort of map_out ----------------
__global__ __launch_bounds__(256) void k_hist(const int* __restrict__ mo, int cnt,
                                              u32* __restrict__ hist) {
  int i = blockIdx.x * 256 + threadIdx.x;
  if (i < cnt) atomicAdd(&hist[mo[i]], 1u);
}

__global__ __launch_bounds__(1024) void k_scan(const u32* __restrict__ hist,
                                               u32* __restrict__ offs) {
  __shared__ u32 tot[1024];
  const int t = threadIdx.x;
  const int PER = NPTS / 1024;  // 128
  const int base = t * PER;
  u32 s = 0;
  for (int i = 0; i < PER; ++i) s += hist[base + i];
  tot[t] = s;
  __syncthreads();
  u32 own = s;
  for (int d = 1; d < 1024; d <<= 1) {
    u32 y = (t >= d) ? tot[t - d] : 0u;
    __syncthreads();
    tot[t] += y;
    __syncthreads();
  }
  u32 run = tot[t] - own;  // exclusive prefix at this thread's first bin
  for (int i = 0; i < PER; ++i) {
    offs[base + i] = run;
    run += hist[base + i];
  }
  if (t == 1023) offs[NPTS] = run;
}

__global__ __launch_bounds__(256) void k_place(const int* __restrict__ mo, int cnt,
                                               const u32* __restrict__ offs,
                                               u32* __restrict__ cur,
                                               u32* __restrict__ perm) {
  int i = blockIdx.x * 256 + threadIdx.x;
  if (i < cnt) {
    int o = mo[i];
    u32 p = offs[o] + atomicAdd(&cur[o], 1u);
    perm[p] = (u32)i;  // entry id relative to chunk == contrib row
  }
}

// ---------------- segmented gather-reduce: one wave per output row ----------------
__global__ __launch_bounds__(256) void k_segreduce(const u16* __restrict__ contrib,
                                                   const u32* __restrict__ offs,
                                                   const u32* __restrict__ perm,
                                                   float* __restrict__ acc) {
  const int wave = threadIdx.x >> 6, lane = threadIdx.x & 63;
  const int row = blockIdx.x * 4 + wave;
  u32 s0 = offs[row], s1 = offs[row + 1];
  float a0 = 0.f, b0 = 0.f, a1 = 0.f, b1 = 0.f;
  u32 e = s0;
  for (; e + 2 <= s1; e += 2) {
    u32 p0 = perm[e], p1 = perm[e + 1];
    u32 d0 = ((const u32*)(contrib + (long)p0 * CD))[lane];
    u32 d1 = ((const u32*)(contrib + (long)p1 * CD))[lane];
    a0 += __uint_as_float(d0 << 16);
    b0 += __uint_as_float(d0 & 0xffff0000u);
    a1 += __uint_as_float(d1 << 16);
    b1 += __uint_as_float(d1 & 0xffff0000u);
  }
  if (e < s1) {
    u32 d0 = ((const u32*)(contrib + (long)perm[e] * CD))[lane];
    a0 += __uint_as_float(d0 << 16);
    b0 += __uint_as_float(d0 & 0xffff0000u);
  }
  float2* op = (float2*)(acc + (long)row * CD) + lane;
  float2 c = *op;
  c.x += a0 + a1;
  c.y += b0 + b1;
  *op = c;
}

// ---------------- batch-norm stats / finalize / apply ----------------
__global__ __launch_bounds__(256) void k_stats(const float* __restrict__ acc,
                                               float* __restrict__ stats) {
  const int t = threadIdx.x;
  const int c = t & 127;
  const int h = t >> 7;
  float s = 0.f, s2 = 0.f;
  const long base = (long)blockIdx.x * 512;
  for (int r = h; r < 512; r += 2) {
    float v = acc[(base + r) * CD + c];
    s += v;
    s2 += v * v;
  }
  __shared__ float sh[256];
  sh[t] = s;
  __syncthreads();
  float ssum = s + ((h == 0) ? sh[t + 128] : 0.f);
  __syncthreads();
  sh[t] = s2;
  __syncthreads();
  if (h == 0) {
    float s2sum = s2 + sh[t + 128];
    atomicAdd(&stats[c], ssum);
    atomicAdd(&stats[128 + c], s2sum);
  }
}

__global__ void k_finalize(const float* __restrict__ stats, const float* __restrict__ gamma,
                           const float* __restrict__ beta, float* __restrict__ scsh) {
  int c = threadIdx.x;  // 128 threads
  float mean = stats[c] * (1.f / NPTS);
  float var = stats[128 + c] * (1.f / NPTS) - mean * mean;
  float sc = rsqrtf(var + 1e-5f) * gamma[c];
  scsh[c] = sc;
  scsh[128 + c] = beta[c] - mean * sc;
}

__device__ __forceinline__ float elu(float v) { return v > 0.f ? v : expf(v) - 1.f; }

__global__ __launch_bounds__(256) void k_apply_mid(const float* __restrict__ acc,
                                                   const float* __restrict__ scsh,
                                                   u16* __restrict__ y) {
  long i = ((long)blockIdx.x * 256 + threadIdx.x) * 4;
  int c = (int)(i & 127);
  float4 a = *(const float4*)(acc + i);
  float r0 = elu(a.x * scsh[c] + scsh[128 + c]);
  float r1 = elu(a.y * scsh[c + 1] + scsh[129 + c]);
  float r2 = elu(a.z * scsh[c + 2] + scsh[130 + c]);
  float r3 = elu(a.w * scsh[c + 3] + scsh[131 + c]);
  uint2 v;
  v.x = f2bf(r0) | ((u32)f2bf(r1) << 16);
  v.y = f2bf(r2) | ((u32)f2bf(r3) << 16);
  *(uint2*)(y + i) = v;
}

__global__ __launch_bounds__(256) void k_apply_final(const float* __restrict__ acc,
                                                     const float* __restrict__ scsh,
                                                     const float* __restrict__ x,
                                                     float* __restrict__ out) {
  long i = ((long)blockIdx.x * 256 + threadIdx.x) * 4;
  int c = (int)(i & 127);
  float4 a = *(const float4*)(acc + i);
  float4 rx = *(const float4*)(x + i);
  float4 o;
  o.x = elu(a.x * scsh[c] + scsh[128 + c] + rx.x);
  o.y = elu(a.y * scsh[c + 1] + scsh[129 + c] + rx.y);
  o.z = elu(a.z * scsh[c + 2] + scsh[130 + c] + rx.z);
  o.w = elu(a.w * scsh[c + 3] + scsh[131 + c] + rx.w);
  *(float4*)(out + i) = o;
}

// ---------------- host ----------------
extern "C" void kernel_launch(void* const* d_in, const int* in_sizes, int n_in,
                              void* d_out, int out_size, void* d_ws, size_t ws_size,
                              hipStream_t stream) {
  const float* x = (const float*)d_in[0];
  const float* W1 = (const float*)d_in[1];
  const float* g1 = (const float*)d_in[2];
  const float* b1 = (const float*)d_in[3];
  const float* W2 = (const float*)d_in[4];
  const float* g2 = (const float*)d_in[5];
  const float* b2 = (const float*)d_in[6];
  const int* m1i = (const int*)d_in[7];
  const int* m1o = (const int*)d_in[8];
  const int* m2i = (const int*)d_in[9];
  const int* m2o = (const int*)d_in[10];
  float* out = (float*)d_out;

  char* base = (char*)d_ws;
  size_t off = 0;
  auto alloc = [&](size_t bytes) -> void* {
    void* r = base + off;
    off = (off + bytes + 255) & ~(size_t)255;
    return r;
  };
  u16* xb = (u16*)alloc((size_t)NPTS * CD * 2);
  u16* yb = (u16*)alloc((size_t)NPTS * CD * 2);
  u16* Wb1 = (u16*)alloc((size_t)KOFF * CD * CD * 2);
  u16* Wb2 = (u16*)alloc((size_t)KOFF * CD * CD * 2);
  float* acc = (float*)alloc((size_t)NPTS * CD * 4);
  u32* hist = (u32*)alloc((size_t)NPTS * 4);
  u32* curb = (u32*)alloc((size_t)NPTS * 4);
  u32* offs = (u32*)alloc(((size_t)NPTS + 1) * 4);
  float* stats = (float*)alloc(256 * 4);
  float* scsh = (float*)alloc(256 * 4);

  // k-chunking to fit scratch: per-k = contrib (16.78MB) + perm (0.26MB)
  size_t per_k = (size_t)MMAP * CD * 2 + (size_t)MMAP * 4 + 1024;
  size_t rem = (ws_size > off + 4096) ? (ws_size - off - 4096) : 0;
  int kcnt = (int)(rem / per_k);
  if (kcnt < 1) kcnt = 1;
  if (kcnt > KOFF) kcnt = KOFF;
  u16* contrib = (u16*)alloc((size_t)kcnt * MMAP * CD * 2);
  u32* perm = (u32*)alloc((size_t)kcnt * MMAP * 4);

  k_convert_x<<<(NPTS * CD) / 2048, 256, 0, stream>>>(x, xb);
  k_convert_w<<<(KOFF * 2048 + 255) / 256, 256, 0, stream>>>(W1, Wb1);
  k_convert_w<<<(KOFF * 2048 + 255) / 256, 256, 0, stream>>>(W2, Wb2);

  auto run_conv = [&](const u16* srcm, const u16* Wbm, const int* mi, const int* mo) {
    hipMemsetAsync(acc, 0, (size_t)NPTS * CD * 4, stream);
    for (int k0 = 0; k0 < KOFF; k0 += kcnt) {
      int kc = (KOFF - k0 < kcnt) ? (KOFF - k0) : kcnt;
      int cnt = kc * MMAP;
      hipMemsetAsync(hist, 0, (size_t)NPTS * 4, stream);
      k_hist<<<(cnt + 255) / 256, 256, 0, stream>>>(mo + (long)k0 * MMAP, cnt, hist);
      k_scan<<<1, 1024, 0, stream>>>(hist, offs);
      hipMemsetAsync(curb, 0, (size_t)NPTS * 4, stream);
      k_place<<<(cnt + 255) / 256, 256, 0, stream>>>(mo + (long)k0 * MMAP, cnt, offs, curb, perm);
      k_gemm<<<dim3(MMAP / 64, kc), 256, 0, stream>>>(srcm, Wbm, mi, contrib, k0);
      k_segreduce<<<NPTS / 4, 256, 0, stream>>>(contrib, offs, perm, acc);
    }
    hipMemsetAsync(stats, 0, 1024, stream);
    k_stats<<<256, 256, 0, stream>>>(acc, stats);
  };

  run_conv(xb, Wb1, m1i, m1o);
  k_finalize<<<1, 128, 0, stream>>>(stats, g1, b1, scsh);
  k_apply_mid<<<(NPTS * CD) / 1024, 256, 0, stream>>>(acc, scsh, yb);

  run_conv(yb, Wb2, m2i, m2o);
  k_finalize<<<1, 128, 0, stream>>>(stats, g2, b2, scsh);
  k_apply_final<<<(NPTS * CD) / 1024, 256, 0, stream>>>(acc, scsh, x, out);
}